// Round 1
// baseline (225.158 us; speedup 1.0000x reference)
//
#include <hip/hip_runtime.h>
#include <cstdint>

#define VOCAB 100000
#define NB    2048
#define SEQ   50
#define HID   256
#define XIN   512
#define NE    64
#define NP    5

#define BEO_BLOCKS 256
#define BEO_ROWS   8
#define NBLK (BEO_BLOCKS + NB)

#define OFF_BOW_E 0
#define OFF_BEO_E (NB*NE)
#define OFF_BOW_P (2*NB*NE)
#define OFF_BEO_P (2*NB*NE + NB*NP)

struct BeoS { float xs[BEO_ROWS][XIN]; };                 // 16 KB (hs reuses this)
struct BowS { int tok[SEQ]; float h[HID]; float part[256]; };
union  SMem { BeoS beo; BowS bow; };

__global__ __launch_bounds__(256) void fused_kernel(
    const int*   __restrict__ s,   const float* __restrict__ x,
    const float* __restrict__ Wbh, const float* __restrict__ bbh,
    const float* __restrict__ Wbp, const float* __restrict__ bbp,
    const float* __restrict__ Wbe, const float* __restrict__ bbe,
    const float* __restrict__ Weh, const float* __restrict__ beh,
    const float* __restrict__ Wep, const float* __restrict__ bep,
    const float* __restrict__ Wee, const float* __restrict__ bee,
    float* __restrict__ out)
{
    __shared__ SMem sm;
    const int tid = threadIdx.x;
    const int blk = blockIdx.x;

    if (blk < BEO_BLOCKS) {
        // ---------------- beo path: 8 batch rows per block ----------------
        const int r0 = blk * BEO_ROWS;
        {
            const float4* src = (const float4*)(x + (size_t)r0 * XIN);
            float4*       dst = (float4*)&sm.beo.xs[0][0];
            #pragma unroll
            for (int i = 0; i < (BEO_ROWS*XIN/4)/256; ++i)
                dst[i*256 + tid] = src[i*256 + tid];
        }
        __syncthreads();

        float acc[BEO_ROWS];
        {
            float bv = beh[tid];
            #pragma unroll
            for (int r = 0; r < BEO_ROWS; ++r) acc[r] = bv;
        }
        for (int k = 0; k < XIN; k += 4) {
            #pragma unroll
            for (int kk = 0; kk < 4; ++kk) {
                float w = Weh[(size_t)(k+kk)*HID + tid];   // coalesced, L2-hot
                #pragma unroll
                for (int r = 0; r < BEO_ROWS; ++r)
                    acc[r] = fmaf(sm.beo.xs[r][k+kk], w, acc[r]);
            }
        }
        __syncthreads();                       // all xs reads done
        float* hs = &sm.beo.xs[0][0];          // reuse LDS as hs[BEO_ROWS][HID]
        #pragma unroll
        for (int r = 0; r < BEO_ROWS; ++r) {
            float v = acc[r];
            hs[r*HID + tid] = v > 0.f ? v : 0.2f*v;
        }
        __syncthreads();

        // embd head: 8 rows x 64 cols -> 2 outputs per thread
        {
            const int jj = tid & 63;
            const int r  = tid >> 6;           // rows r and r+4
            float s0 = 0.f, s1 = 0.f;
            for (int k = 0; k < HID; ++k) {
                float w = Wee[k*NE + jj];
                s0 = fmaf(hs[r*HID + k],     w, s0);
                s1 = fmaf(hs[(r+4)*HID + k], w, s1);
            }
            float bias = bee[jj];
            out[OFF_BEO_E + (size_t)(r0+r)*NE   + jj] = s0 + bias;
            out[OFF_BEO_E + (size_t)(r0+r+4)*NE + jj] = s1 + bias;
        }
        // pred head: 8 rows x 5 cols
        if (tid < BEO_ROWS*NP) {
            const int r = tid / NP, jj = tid % NP;
            float sp = bep[jj];
            for (int k = 0; k < HID; ++k)
                sp = fmaf(hs[r*HID + k], Wep[k*NP + jj], sp);
            out[OFF_BEO_P + (size_t)(r0+r)*NP + jj] = sp;
        }
    } else {
        // ---------------- bow path: 1 batch row per block ----------------
        const int row = blk - BEO_BLOCKS;
        if (tid < SEQ) sm.bow.tok[tid] = s[row*SEQ + tid];
        __syncthreads();
        int myt = -1;
        if (tid < SEQ) {
            myt = sm.bow.tok[tid];
            for (int i = 0; i < tid; ++i)
                if (sm.bow.tok[i] == myt) myt = -1;   // later duplicate -> drop
        }
        __syncthreads();
        if (tid < SEQ) sm.bow.tok[tid] = myt;
        __syncthreads();

        float acc = bbh[tid];
        #pragma unroll
        for (int i = 0; i < SEQ; ++i) {
            int t = sm.bow.tok[i];
            float m = (t >= 0) ? 1.0f : 0.0f;        // branchless dedup mask
            int  ts = (t < 0) ? 0 : t;
            acc = fmaf(m, Wbh[(size_t)ts*HID + tid], acc);  // 1KB-row gather
        }
        float hv = acc > 0.f ? acc : 0.2f*acc;
        sm.bow.h[tid] = hv;
        __syncthreads();

        // embd head: 64 outs, 4 partials each (all 4 waves busy)
        {
            const int jj = tid & 63, p = tid >> 6;
            float ps = 0.f;
            #pragma unroll 8
            for (int kk = 0; kk < 64; ++kk) {
                int k = p*64 + kk;
                ps = fmaf(sm.bow.h[k], Wbe[k*NE + jj], ps);
            }
            sm.bow.part[tid] = ps;
        }
        __syncthreads();
        // pred partials: 5 outs x 8 partials (threads 0..39), reads h only
        float pp = 0.f;
        if (tid < 8*NP) {
            const int p = tid / NP, jj = tid % NP;
            #pragma unroll 8
            for (int kk = 0; kk < 32; ++kk) {
                int k = p*32 + kk;
                pp = fmaf(sm.bow.h[k], Wbp[k*NP + jj], pp);
            }
        }
        // embd reduce (part still holds embd partials here)
        if (tid < NE) {
            float e = sm.bow.part[tid] + sm.bow.part[tid+64]
                    + sm.bow.part[tid+128] + sm.bow.part[tid+192] + bbe[tid];
            out[OFF_BOW_E + (size_t)row*NE + tid] = e;
        }
        __syncthreads();
        if (tid < 8*NP) sm.bow.part[tid] = pp;
        __syncthreads();
        if (tid < NP) {
            float sp = bbp[tid];
            #pragma unroll
            for (int q = 0; q < 8; ++q) sp += sm.bow.part[q*NP + tid];
            out[OFF_BOW_P + (size_t)row*NP + tid] = sp;
        }
    }
}

extern "C" void kernel_launch(void* const* d_in, const int* in_sizes, int n_in,
                              void* d_out, int out_size, void* d_ws, size_t ws_size,
                              hipStream_t stream) {
    const int*   s   = (const int*)  d_in[0];
    const float* x   = (const float*)d_in[1];
    const float* Wbh = (const float*)d_in[2];
    const float* bbh = (const float*)d_in[3];
    const float* Wbp = (const float*)d_in[4];
    const float* bbp = (const float*)d_in[5];
    const float* Wbe = (const float*)d_in[6];
    const float* bbe = (const float*)d_in[7];
    const float* Weh = (const float*)d_in[8];
    const float* beh = (const float*)d_in[9];
    const float* Wep = (const float*)d_in[10];
    const float* bep = (const float*)d_in[11];
    const float* Wee = (const float*)d_in[12];
    const float* bee = (const float*)d_in[13];

    fused_kernel<<<dim3(NBLK), dim3(256), 0, stream>>>(
        s, x, Wbh, bbh, Wbp, bbp, Wbe, bbe,
        Weh, beh, Wep, bep, Wee, bee, (float*)d_out);
}